// Round 4
// baseline (15.935 us; speedup 1.0000x reference)
//
#include <hip/hip_runtime.h>

// PlaceCellNetwork — closed-form fixed point (see round-2 derivation):
//   Y[n,j] = max( X[n,:].W[j,:] - b[j], 0 ) / (denom_j + dM_j)
// Memory-bound: 3 MB read + 21 MB write. Round-2 kernel hit only 2.2 TB/s
// (fillBuffer proves ~6.7 TB/s achievable). This round: grid-stride with
// per-thread-invariant jb (stride divisible by 5), 4 independent float4
// nontemporal stores per thread, X loads hoisted for MLP.
// (Round-3 fix: __builtin_nontemporal_store needs a native ext_vector type,
// not HIP_vector_type<float,4>.)

#define PCN_N    262144
#define PCN_DIN  3
#define PCN_DOUT 20

#define BLOCK 256
#define GRID  1280
#define PER_THREAD 4
#define SWEEP (GRID * BLOCK)          // 327,680 float4 slots; divisible by 5
#define N_STEP (SWEEP / 5)            // 65,536 rows per sweep

typedef float fvec4 __attribute__((ext_vector_type(4)));

__global__ __launch_bounds__(BLOCK)
void pcn_closed_kernel(const float* __restrict__ X,
                       const float* __restrict__ W,
                       const float* __restrict__ M,
                       const float* __restrict__ b,
                       float* __restrict__ Yout) {
    constexpr float ALPHA = 1.0f, LBD2 = 0.0f;

    // c[j] = {w0,w1,w2,-alpha*b[j]} * 1/(denom+dM); pad to 5 to avoid bank
    // aliasing for jb in {0,4,8,12,16}.
    __shared__ float c[PCN_DOUT][5];
    int t = threadIdx.x;
    if (t < PCN_DOUT) {
        float dM = M[t * PCN_DOUT + t];
        float inv = 1.0f / ((LBD2 + dM) + dM);
        c[t][0] = W[t * PCN_DIN + 0] * inv;
        c[t][1] = W[t * PCN_DIN + 1] * inv;
        c[t][2] = W[t * PCN_DIN + 2] * inv;
        c[t][3] = -ALPHA * b[t] * inv;
    }
    __syncthreads();

    int idx0 = blockIdx.x * BLOCK + threadIdx.x;   // float4 slot, sweep 0
    int n0   = idx0 / 5;
    int jb   = (idx0 - n0 * 5) * 4;                // invariant across sweeps

    // Preload this lane's 4 coefficient rows into registers.
    float c0[4], c1[4], c2[4], c3[4];
    #pragma unroll
    for (int k = 0; k < 4; ++k) {
        c0[k] = c[jb + k][0];
        c1[k] = c[jb + k][1];
        c2[k] = c[jb + k][2];
        c3[k] = c[jb + k][3];
    }

    // Hoist all X loads (12 independent dword loads in flight).
    float x0[PER_THREAD], x1[PER_THREAD], x2[PER_THREAD];
    #pragma unroll
    for (int it = 0; it < PER_THREAD; ++it) {
        int n = n0 + it * N_STEP;
        x0[it] = X[n * PCN_DIN + 0];
        x1[it] = X[n * PCN_DIN + 1];
        x2[it] = X[n * PCN_DIN + 2];
    }

    fvec4* __restrict__ Y4 = reinterpret_cast<fvec4*>(Yout);
    #pragma unroll
    for (int it = 0; it < PER_THREAD; ++it) {
        fvec4 o;
        o.x = fmaxf(fmaf(x0[it], c0[0], fmaf(x1[it], c1[0], fmaf(x2[it], c2[0], c3[0]))), 0.0f);
        o.y = fmaxf(fmaf(x0[it], c0[1], fmaf(x1[it], c1[1], fmaf(x2[it], c2[1], c3[1]))), 0.0f);
        o.z = fmaxf(fmaf(x0[it], c0[2], fmaf(x1[it], c1[2], fmaf(x2[it], c2[2], c3[2]))), 0.0f);
        o.w = fmaxf(fmaf(x0[it], c0[3], fmaf(x1[it], c1[3], fmaf(x2[it], c2[3], c3[3]))), 0.0f);
        __builtin_nontemporal_store(o, Y4 + idx0 + it * SWEEP);
    }
}

extern "C" void kernel_launch(void* const* d_in, const int* in_sizes, int n_in,
                              void* d_out, int out_size, void* d_ws, size_t ws_size,
                              hipStream_t stream) {
    const float* X = (const float*)d_in[0];
    const float* W = (const float*)d_in[1];
    const float* M = (const float*)d_in[2];
    const float* b = (const float*)d_in[3];
    float* Yout = (float*)d_out;

    // GRID*BLOCK*PER_THREAD == N*DOUT/4 exactly (1,310,720 float4 stores)
    pcn_closed_kernel<<<GRID, BLOCK, 0, stream>>>(X, W, M, b, Yout);
}

// Round 5
// 13.376 us; speedup vs baseline: 1.1913x; 1.1913x over previous
//
#include <hip/hip_runtime.h>

// PlaceCellNetwork — closed-form fixed point (see round-2 derivation):
//   Y[n,j] = max( X[n,:].W[j,:] - b[j], 0 ) / (denom_j + dM_j)
// Memory-bound: 3 MB read + 21 MB write.
// Round-4 post-mortem: nontemporal stores bypassed L2 write-combining and
// cost +5 us (15.9 vs 10.9). This round: identical structure, PLAIN stores.

#define PCN_N    262144
#define PCN_DIN  3
#define PCN_DOUT 20

#define BLOCK 256
#define GRID  1280
#define PER_THREAD 4
#define SWEEP (GRID * BLOCK)          // 327,680 float4 slots; divisible by 5
#define N_STEP (SWEEP / 5)            // 65,536 rows per sweep

typedef float fvec4 __attribute__((ext_vector_type(4)));

__global__ __launch_bounds__(BLOCK)
void pcn_closed_kernel(const float* __restrict__ X,
                       const float* __restrict__ W,
                       const float* __restrict__ M,
                       const float* __restrict__ b,
                       float* __restrict__ Yout) {
    constexpr float ALPHA = 1.0f, LBD2 = 0.0f;

    // c[j] = {w0,w1,w2,-alpha*b[j]} * 1/(denom+dM); pad to 5 to avoid bank
    // aliasing for jb in {0,4,8,12,16}.
    __shared__ float c[PCN_DOUT][5];
    int t = threadIdx.x;
    if (t < PCN_DOUT) {
        float dM = M[t * PCN_DOUT + t];
        float inv = 1.0f / ((LBD2 + dM) + dM);
        c[t][0] = W[t * PCN_DIN + 0] * inv;
        c[t][1] = W[t * PCN_DIN + 1] * inv;
        c[t][2] = W[t * PCN_DIN + 2] * inv;
        c[t][3] = -ALPHA * b[t] * inv;
    }
    __syncthreads();

    int idx0 = blockIdx.x * BLOCK + threadIdx.x;   // float4 slot, sweep 0
    int n0   = idx0 / 5;
    int jb   = (idx0 - n0 * 5) * 4;                // invariant across sweeps

    // Preload this lane's 4 coefficient rows into registers.
    float c0[4], c1[4], c2[4], c3[4];
    #pragma unroll
    for (int k = 0; k < 4; ++k) {
        c0[k] = c[jb + k][0];
        c1[k] = c[jb + k][1];
        c2[k] = c[jb + k][2];
        c3[k] = c[jb + k][3];
    }

    // Hoist all X loads (12 independent dword loads in flight).
    float x0[PER_THREAD], x1[PER_THREAD], x2[PER_THREAD];
    #pragma unroll
    for (int it = 0; it < PER_THREAD; ++it) {
        int n = n0 + it * N_STEP;
        x0[it] = X[n * PCN_DIN + 0];
        x1[it] = X[n * PCN_DIN + 1];
        x2[it] = X[n * PCN_DIN + 2];
    }

    fvec4* __restrict__ Y4 = reinterpret_cast<fvec4*>(Yout);
    #pragma unroll
    for (int it = 0; it < PER_THREAD; ++it) {
        fvec4 o;
        o.x = fmaxf(fmaf(x0[it], c0[0], fmaf(x1[it], c1[0], fmaf(x2[it], c2[0], c3[0]))), 0.0f);
        o.y = fmaxf(fmaf(x0[it], c0[1], fmaf(x1[it], c1[1], fmaf(x2[it], c2[1], c3[1]))), 0.0f);
        o.z = fmaxf(fmaf(x0[it], c0[2], fmaf(x1[it], c1[2], fmaf(x2[it], c2[2], c3[2]))), 0.0f);
        o.w = fmaxf(fmaf(x0[it], c0[3], fmaf(x1[it], c1[3], fmaf(x2[it], c2[3], c3[3]))), 0.0f);
        Y4[idx0 + it * SWEEP] = o;   // plain store: let L2 write-combine
    }
}

extern "C" void kernel_launch(void* const* d_in, const int* in_sizes, int n_in,
                              void* d_out, int out_size, void* d_ws, size_t ws_size,
                              hipStream_t stream) {
    const float* X = (const float*)d_in[0];
    const float* W = (const float*)d_in[1];
    const float* M = (const float*)d_in[2];
    const float* b = (const float*)d_in[3];
    float* Yout = (float*)d_out;

    // GRID*BLOCK*PER_THREAD == N*DOUT/4 exactly (1,310,720 float4 stores)
    pcn_closed_kernel<<<GRID, BLOCK, 0, stream>>>(X, W, M, b, Yout);
}